// Round 3
// baseline (398.351 us; speedup 1.0000x reference)
//
#include <hip/hip_runtime.h>
#include <hip/hip_bf16.h>
#include <stdint.h>

typedef unsigned short ushort_t;
typedef __attribute__((ext_vector_type(8))) short short8;
typedef __attribute__((ext_vector_type(4))) float floatx4;
typedef __attribute__((ext_vector_type(2))) float floatx2;

__device__ __forceinline__ float bf2f(unsigned short u){
  union { unsigned int i; float f; } v; v.i = ((unsigned int)u) << 16; return v.f;
}
__device__ __forceinline__ unsigned short f2bf(float f){
  union { float f; unsigned int i; } v; v.f = f;
  unsigned int r = v.i + 0x7FFFu + ((v.i >> 16) & 1u);
  return (unsigned short)(r >> 16);
}
__device__ __forceinline__ unsigned int pack2(unsigned short lo, unsigned short hi){
  return ((unsigned int)hi << 16) | (unsigned int)lo;
}
// 2-op bf16-pair unpack: lo half = v<<16, hi half = v & 0xffff0000
__device__ __forceinline__ float bflo(unsigned int v){
  union { unsigned int u; float f; } c; c.u = v << 16; return c.f;
}
__device__ __forceinline__ float bfhi(unsigned int v){
  union { unsigned int u; float f; } c; c.u = v & 0xffff0000u; return c.f;
}
// packed bf16-pair -> float2 (2 VALU ops); accumulate via v_pk_add_f32 (1 op)
__device__ __forceinline__ floatx2 bfpair(unsigned int v){
  union { unsigned int u; float f; } lo, hi;
  lo.u = v << 16; hi.u = v & 0xffff0000u;
  floatx2 r; r.x = lo.f; r.y = hi.f; return r;
}

// ---------------- prep kernel: [bucket histogram | x->bf16 | weight perm] by block range ----------------
// Per-block int64/int32 storage detect: OR 4096 odd words of this block's span
// (int64 storage => all-zero high halves; P(false positive | int32) ~ (1e-5)^2560 ~ 0).

__global__ __launch_bounds__(256)
void k_prep(const unsigned int* __restrict__ w, int* __restrict__ ghist, int E, int N, int nbB,
            const float2* __restrict__ xin, unsigned int* __restrict__ xb, int total2, int tobfB,
            const float* __restrict__ W1a, const float* __restrict__ W1b, const float* __restrict__ W2a,
            const float* __restrict__ W2b, const float* __restrict__ W3a, const float* __restrict__ W3b,
            const float* __restrict__ Wfc, ushort_t* __restrict__ wout)
{
  int b = blockIdx.x, t = threadIdx.x;
  if (b < nbB){
    __shared__ int h[256];
    __shared__ unsigned int dred[4];
    h[t] = 0;
    int base = b*4096 + t;
    unsigned int acc = 0;
    #pragma unroll
    for (int i=0;i<16;++i){
      int e = base + i*256;
      if (e < E) acc |= w[2*e+1];
    }
    #pragma unroll
    for (int o=32;o>=1;o>>=1) acc |= __shfl_xor(acc, o);
    if ((t&63)==0) dred[t>>6] = acc;
    __syncthreads();
    int m = (dred[0]|dred[1]|dred[2]|dred[3]) != 0;   // 1 => int32 words
    #pragma unroll
    for (int i=0;i<16;++i){
      int e = base + i*256;
      if (e < E){
        int d = m ? (int)w[(size_t)E + e] : (int)w[2*((size_t)E + e)];
        if ((unsigned)d < (unsigned)N) atomicAdd(&h[d>>9], 1);
      }
    }
    __syncthreads();
    if (h[t]) atomicAdd(&ghist[t], h[t]);
  } else if (b < nbB + tobfB){
    int i = (b - nbB)*256 + t;
    if (i < total2){
      float2 v = xin[i];
      xb[i] = pack2(f2bf(v.x), f2bf(v.y));
    }
  } else {
    int id = (b - nbB - tobfB)*256 + t;
    const float* src; int K, M, base2, local;
    if      (id <  8192){ src=W1a; K=64;  M=128; base2=0;     local=id; }
    else if (id < 24576){ src=W1b; K=128; M=128; base2=8192;  local=id-8192; }
    else if (id < 40960){ src=W2a; K=128; M=128; base2=24576; local=id-24576; }
    else if (id < 57344){ src=W2b; K=128; M=128; base2=40960; local=id-40960; }
    else if (id < 65536){ src=W3a; K=128; M=64;  base2=57344; local=id-57344; }
    else if (id < 69632){ src=W3b; K=64;  M=64;  base2=65536; local=id-65536; }
    else if (id < 70656){ src=Wfc; K=64;  M=16;  base2=69632; local=id-69632; }
    else return;
    int k = local / M, nn = local - k*M;
    float val;
    if (src == Wfc) val = (nn<8) ? Wfc[k*8+nn] : 0.0f;
    else            val = src[k*M+nn];
    int idx = (((nn>>4)*(K/32) + (k>>5))*4 + ((k>>3)&3))*128 + (nn&15)*8 + (k&7);
    wout[base2+idx] = f2bf(val);
  }
}

// ---------------- CSR build via 512-node bucket counting sort ----------------

__global__ __launch_bounds__(256) void k_bscan(const int* __restrict__ ghist, int* __restrict__ bbase,
                                               int* __restrict__ gcur, int NB){
  __shared__ int sv[256];
  int t = threadIdx.x;
  int v = (t < NB) ? ghist[t] : 0;
  sv[t] = v; __syncthreads();
  for (int o=1;o<256;o<<=1){
    int xv = (t>=o)? sv[t-o] : 0;
    __syncthreads();
    sv[t] += xv;
    __syncthreads();
  }
  int excl = sv[t] - v;
  if (t < NB){ bbase[t] = excl; gcur[t] = excl; }
  if (t == NB-1) bbase[NB] = excl + v;
}

__global__ __launch_bounds__(256) void k_bin(const unsigned int* __restrict__ w,
                                             int* __restrict__ gcur, int2* __restrict__ pairs,
                                             int E, int N, int NB){
  __shared__ int h[256];
  __shared__ int cur[256];
  __shared__ unsigned int dred[4];
  int t = threadIdx.x;
  h[t] = 0;
  int base = blockIdx.x*4096 + t;
  unsigned int acc = 0;
  #pragma unroll
  for (int i=0;i<16;++i){
    int e = base + i*256;
    if (e < E) acc |= w[2*e+1];
  }
  #pragma unroll
  for (int o=32;o>=1;o>>=1) acc |= __shfl_xor(acc, o);
  if ((t&63)==0) dred[t>>6] = acc;
  __syncthreads();
  int m = (dred[0]|dred[1]|dred[2]|dred[3]) != 0;
  int d[16], s[16];
  #pragma unroll
  for (int i=0;i<16;++i){
    int e = base + i*256;
    d[i] = -1; s[i] = 0;
    if (e < E){
      if (m){ s[i] = (int)w[e];           d[i] = (int)w[(size_t)E + e]; }
      else  { s[i] = (int)w[2*(size_t)e]; d[i] = (int)w[2*((size_t)E + e)]; }
      if ((unsigned)d[i] >= (unsigned)N || (unsigned)s[i] >= (unsigned)N) d[i] = -1;
    }
  }
  #pragma unroll
  for (int i=0;i<16;++i)
    if (d[i] >= 0) atomicAdd(&h[d[i]>>9], 1);
  __syncthreads();
  if (t < NB && h[t]) cur[t] = atomicAdd(&gcur[t], h[t]);
  __syncthreads();
  #pragma unroll
  for (int i=0;i<16;++i){
    if (d[i] >= 0){
      int p = atomicAdd(&cur[d[i]>>9], 1);
      pairs[p] = make_int2(d[i], s[i]);
    }
  }
}

__global__ __launch_bounds__(256) void k_bcsr(const int2* __restrict__ pairs, const int* __restrict__ bbase,
                                              int* __restrict__ offs, int* __restrict__ csr, int N, int NB){
  __shared__ int cnt[512];
  __shared__ int wsum[4];
  int b = blockIdx.x, t = threadIdx.x, lane = t&63, wv = t>>6;
  int lo = bbase[b], hi = bbase[b+1];
  int node0 = b << 9;
  cnt[t] = 0; cnt[t+256] = 0;
  __syncthreads();
  for (int i = lo+t; i < hi; i += 256){
    int2 p = pairs[i];
    atomicAdd(&cnt[p.x - node0], 1);
  }
  __syncthreads();
  int v0 = cnt[2*t], v1 = cnt[2*t+1], tot = v0+v1;
  int s = tot;
  #pragma unroll
  for (int o=1;o<64;o<<=1){ int xv = __shfl_up(s,o); if (lane>=o) s += xv; }
  if (lane==63) wsum[wv] = s;
  __syncthreads();
  int basev = 0;
  for (int j=0;j<wv;++j) basev += wsum[j];
  int excl = basev + s - tot;
  int e0 = lo + excl, e1 = lo + excl + v0;
  cnt[2*t] = e0; cnt[2*t+1] = e1;
  int n0 = node0 + 2*t, n1 = node0 + 2*t + 1;
  if (n0 < N) offs[n0] = e0;
  if (n1 < N) offs[n1] = e1;
  if (b == NB-1 && t == 255) offs[N] = hi;
  __syncthreads();
  for (int i = lo+t; i < hi; i += 256){
    int2 p = pairs[i];
    int pos = atomicAdd(&cnt[p.x - node0], 1);
    csr[pos] = p.y;
  }
}

// ------------- gather: shfl-distributed csr + uint4 rows + packed-f32 accumulate -------------
// Per node: one coalesced csr chunk load (padded with zero-row index), then ceil(deg/16) groups
// of 16 edges, 2-deep software-pipelined (A/B register buffers, 8 row loads in flight/lane).
// Accumulation in float2 (v_pk_add_f32): 3 VALU per bf16 pair vs 4 scalar.

template<int F>
__global__ __launch_bounds__(256) void k_gatherx(const uint4* __restrict__ xr, const int* __restrict__ offs,
                                                 const int* __restrict__ csr, const float* __restrict__ epsp,
                                                 uint4* __restrict__ hr, int n, int nzrow){
  constexpr int RS  = F/8;           // uint4 per row: 16 (F=128), 8 (F=64)
  constexpr int LPN = 4*RS;          // lanes per node: 64 (F=128), 32 (F=64)
  constexpr int NPW = 64/LPN;        // nodes per wave: 1 or 2
  constexpr int CH  = LPN;           // csr entries per chunk
  constexpr int MAXG = CH/16;        // groups per chunk: 4 (F=128), 2 (F=64)
  int gt = blockIdx.x*256 + threadIdx.x;
  int wv = gt >> 6, lane = gt & 63;
  int grp = lane / LPN;              // node within wave
  int lin = lane % LPN;              // lane within node
  int q   = lin / RS;                // quarter 0..3
  int f   = lin % RS;                // uint4 index within row
  int node = wv*NPW + grp;
  if (node >= n) return;
  const size_t row = (size_t)node*RS;
  float e1s = 1.0f + epsp[0];
  floatx2 a0,a1,a2,a3;
  if (q == 0){
    uint4 sv = xr[row + f];
    floatx2 es; es.x = e1s; es.y = e1s;
    a0 = es*bfpair(sv.x); a1 = es*bfpair(sv.y);
    a2 = es*bfpair(sv.z); a3 = es*bfpair(sv.w);
  } else {
    floatx2 z; z.x = 0.f; z.y = 0.f;
    a0 = z; a1 = z; a2 = z; a3 = z;
  }
  int u0 = offs[node], u1 = offs[node+1];
  int deg = u1 - u0;

#define ISSUE(g, V0,V1,V2,V3) { int bb = grp*LPN + (g)*16 + q; \
    int s0=__shfl(cv,bb), s1=__shfl(cv,bb+4), s2=__shfl(cv,bb+8), s3=__shfl(cv,bb+12); \
    V0 = xr[(size_t)s0*RS + f]; V1 = xr[(size_t)s1*RS + f]; \
    V2 = xr[(size_t)s2*RS + f]; V3 = xr[(size_t)s3*RS + f]; }
#define ACCV(V)  { a0 += bfpair((V).x); a1 += bfpair((V).y); a2 += bfpair((V).z); a3 += bfpair((V).w); }
#define ACC4(V0,V1,V2,V3) { ACCV(V0) ACCV(V1) ACCV(V2) ACCV(V3) }

  for (int c0 = 0; c0 < deg; c0 += CH){
    int rem = deg - c0;
    int cv = nzrow;                          // padded entries gather the zeroed row
    if (lin < rem) cv = csr[u0 + c0 + lin];  // one coalesced load covers the chunk
    int nk = rem < CH ? rem : CH;
    int ng = (nk + 15) >> 4;                 // uniform within a node
    uint4 A0,A1,A2,A3, B0,B1,B2,B3;
    ISSUE(0, A0,A1,A2,A3)
    if (ng > 1) { ISSUE(1, B0,B1,B2,B3) }
    ACC4(A0,A1,A2,A3)
    if (ng > 1){
      if constexpr (MAXG >= 3) { if (ng > 2) ISSUE(2, A0,A1,A2,A3) }
      ACC4(B0,B1,B2,B3)
      if constexpr (MAXG >= 3){
        if (ng > 2){
          if (ng > 3) { ISSUE(3, B0,B1,B2,B3) }
          ACC4(A0,A1,A2,A3)
          if (ng > 3) { ACC4(B0,B1,B2,B3) }
        }
      }
    }
  }
#undef ISSUE
#undef ACCV
#undef ACC4
  // reduce partial sums across the 4 quarter-groups
#define RED(av) { av.x += __shfl_xor(av.x, RS);   av.y += __shfl_xor(av.y, RS); \
                  av.x += __shfl_xor(av.x, 2*RS); av.y += __shfl_xor(av.y, 2*RS); }
  RED(a0) RED(a1) RED(a2) RED(a3)
#undef RED
  if (q == 0){
    uint4 o;
    o.x = pack2(f2bf(a0.x), f2bf(a0.y));
    o.y = pack2(f2bf(a1.x), f2bf(a1.y));
    o.z = pack2(f2bf(a2.x), f2bf(a2.y));
    o.w = pack2(f2bf(a3.x), f2bf(a3.y));
    hr[row + f] = o;
  }
}

// ---------------- fused MFMA MLP: x_next = relu(relu(h@Wa+ba)@Wb+bb); LAST adds emb(f32)+FC(f32) ----------------

template<int F, int M1, int M2, bool LAST>
__global__ __launch_bounds__(256)
void k_mlp(const ushort_t* __restrict__ h,
           const ushort_t* __restrict__ wp1, const float* __restrict__ b1,
           const ushort_t* __restrict__ wp2, const float* __restrict__ b2,
           ushort_t* __restrict__ xout,      // !LAST: bf16 next-layer x
           float* __restrict__ embp,         // LAST: f32 emb
           const ushort_t* __restrict__ wpfc, const float* __restrict__ bfc,
           float* __restrict__ outp, int n)
{
  constexpr int NT1 = M1/16, NT2 = M2/16, KC1 = F/32, KC2 = M1/32;
  __shared__ short sC1[4*(M1/8)*136];
  __shared__ short sX3[LAST ? (4*8*136) : 1];
  int tid = threadIdx.x, lane = tid&63, w = tid>>6;
  int m16 = lane&15, quad = lane>>4;
  int row0 = blockIdx.x*64 + w*16;
  size_t arow = (size_t)(row0 + m16);

  floatx4 acc[NT1];
  #pragma unroll
  for (int i=0;i<NT1;++i) acc[i] = (floatx4){0.f,0.f,0.f,0.f};
  #pragma unroll
  for (int kc=0; kc<KC1; ++kc){
    short8 a = *(const short8*)(h + arow*F + kc*32 + quad*8);
    #pragma unroll
    for (int nt=0; nt<NT1; ++nt){
      short8 b = *(const short8*)(wp1 + (size_t)((nt*KC1+kc)*64 + lane)*8);
      acc[nt] = __builtin_amdgcn_mfma_f32_16x16x32_bf16(a, b, acc[nt], 0, 0, 0);
    }
  }
  #pragma unroll
  for (int nt=0; nt<NT1; ++nt){
    int c = nt*16 + m16;
    float bias = b1[c];
    #pragma unroll
    for (int r=0;r<4;++r){
      float v = fmaxf(acc[nt][r] + bias, 0.f);
      int mm = quad*4 + r;
      sC1[(w*(M1/8) + (c>>3))*136 + mm*8 + (c&7)] = (short)f2bf(v);
    }
  }
  __syncthreads();

  floatx4 acc2[NT2];
  #pragma unroll
  for (int i=0;i<NT2;++i) acc2[i] = (floatx4){0.f,0.f,0.f,0.f};
  #pragma unroll
  for (int kc=0; kc<KC2; ++kc){
    short8 a = *(const short8*)&sC1[(w*(M1/8) + kc*4 + quad)*136 + m16*8];
    #pragma unroll
    for (int nt=0; nt<NT2; ++nt){
      short8 b = *(const short8*)(wp2 + (size_t)((nt*KC2+kc)*64 + lane)*8);
      acc2[nt] = __builtin_amdgcn_mfma_f32_16x16x32_bf16(a, b, acc2[nt], 0, 0, 0);
    }
  }
  #pragma unroll
  for (int nt=0; nt<NT2; ++nt){
    int c = nt*16 + m16;
    float bias = b2[c];
    #pragma unroll
    for (int r=0;r<4;++r){
      float v = fmaxf(acc2[nt][r] + bias, 0.f);
      int mm = quad*4 + r;
      int row = row0 + mm;
      if constexpr (!LAST){
        if (row < n) xout[(size_t)row*M2 + c] = f2bf(v);
      } else {
        if (row < n) embp[(size_t)row*64 + c] = v;                // f32 emb
        sX3[(w*8 + (c>>3))*136 + mm*8 + (c&7)] = (short)f2bf(v);
      }
    }
  }

  if constexpr (LAST){
    __syncthreads();
    floatx4 accf = (floatx4){0.f,0.f,0.f,0.f};
    #pragma unroll
    for (int kc=0; kc<2; ++kc){
      short8 a = *(const short8*)&sX3[(w*8 + kc*4 + quad)*136 + m16*8];
      short8 b = *(const short8*)(wpfc + (size_t)(kc*64 + lane)*8);
      accf = __builtin_amdgcn_mfma_f32_16x16x32_bf16(a, b, accf, 0, 0, 0);
    }
    if (m16 < 8){
      float bias = bfc[m16];
      #pragma unroll
      for (int r=0;r<4;++r){
        int row = row0 + quad*4 + r;
        if (row < n) outp[(size_t)row*8 + m16] = accf[r] + bias;  // f32 out
      }
    }
  }
}

// ---------------- launcher ----------------

extern "C" void kernel_launch(void* const* d_in, const int* in_sizes, int n_in,
                              void* d_out, int out_size, void* d_ws, size_t ws_size,
                              hipStream_t stream)
{
  const int N = in_sizes[0] / 64;
  const int E = in_sizes[1] / 2;
  const int NB = (N + 511) / 512;
  const float*        x    = (const float*)d_in[0];
  const unsigned int* ew   = (const unsigned int*)d_in[1];
  const float* eps1 = (const float*)d_in[2];
  const float* eps2 = (const float*)d_in[3];
  const float* eps3 = (const float*)d_in[4];
  const float* W1a  = (const float*)d_in[5];
  const float* b1a  = (const float*)d_in[6];
  const float* W1b  = (const float*)d_in[7];
  const float* b1b  = (const float*)d_in[8];
  const float* W2a  = (const float*)d_in[9];
  const float* b2a  = (const float*)d_in[10];
  const float* W2b  = (const float*)d_in[11];
  const float* b2b  = (const float*)d_in[12];
  const float* W3a  = (const float*)d_in[13];
  const float* b3a  = (const float*)d_in[14];
  const float* W3b  = (const float*)d_in[15];
  const float* b3b  = (const float*)d_in[16];
  const float* Wfc  = (const float*)d_in[17];
  const float* bfc  = (const float*)d_in[18];

  float* outp = (float*)d_out;                 // f32 output (verified round 6)
  float* emb  = outp + (size_t)N*8;

  const int Npad = ((N + 63)/64)*64;

  char* ws = (char*)d_ws;
  size_t o = 0;
  auto alloc = [&](size_t bytes)->char* {
    char* p = ws + o;
    o = (o + bytes + 255) & ~(size_t)255;
    return p;
  };
  int*      ghist = (int*)alloc(256*4);
  int*      bbase = (int*)alloc(257*4);
  int*      gcur  = (int*)alloc(256*4);
  int*      offs  = (int*)alloc((size_t)(N+1)*4);
  int2*     pairs = (int2*)alloc((size_t)E*8);
  int*      csr   = (int*)alloc((size_t)E*4);
  ushort_t* wperm = (ushort_t*)alloc(70656ull*2);
  ushort_t* xb    = (ushort_t*)alloc(((size_t)Npad + 64)*64*2);    // bf16 copy of x (+zero row)
  ushort_t* hbuf  = (ushort_t*)alloc((size_t)Npad*128*2);          // gather output (bf16)
  ushort_t* x1    = (ushort_t*)alloc(((size_t)Npad + 64)*128*2);   // layer outputs (bf16, +zero row)

  hipMemsetAsync(ghist, 0, 256*4, stream);
  // zero dummy row (index N) used by the gather for padded edge slots
  hipMemsetAsync(xb + (size_t)N*64, 0, 64*2, stream);
  hipMemsetAsync(x1 + (size_t)N*128, 0, 128*2, stream);
  const int nbB   = (E + 4095)/4096;
  const int tobfB = (N*32 + 255)/256;
  const int permB = 70656/256;
  k_prep<<<nbB + tobfB + permB, 256, 0, stream>>>(ew, ghist, E, N, nbB,
                                                  (const float2*)x, (unsigned int*)xb, N*32, tobfB,
                                                  W1a, W1b, W2a, W2b, W3a, W3b, Wfc, wperm);
  k_bscan<<<1, 256, 0, stream>>>(ghist, bbase, gcur, NB);
  k_bin<<<nbB, 256, 0, stream>>>(ew, gcur, pairs, E, N, NB);
  k_bcsr<<<NB, 256, 0, stream>>>(pairs, bbase, offs, csr, N, NB);

  // layer 1 (64 -> 128): gather F=64 (2 nodes/wave)
  k_gatherx<64><<<(N+7)/8, 256, 0, stream>>>((const uint4*)xb, offs, csr, eps1,
                                             (uint4*)hbuf, N, N);
  k_mlp<64,128,128,false><<<Npad/64, 256, 0, stream>>>(hbuf, wperm+0, b1a, wperm+8192, b1b,
                                                       x1, nullptr, nullptr, nullptr, nullptr, N);
  // layer 2 (128 -> 128)
  k_gatherx<128><<<(N+3)/4, 256, 0, stream>>>((const uint4*)x1, offs, csr, eps2,
                                              (uint4*)hbuf, N, N);
  k_mlp<128,128,128,false><<<Npad/64, 256, 0, stream>>>(hbuf, wperm+24576, b2a, wperm+40960, b2b,
                                                        x1, nullptr, nullptr, nullptr, nullptr, N);
  // layer 3 (128 -> 64) + FC (64 -> 8)
  k_gatherx<128><<<(N+3)/4, 256, 0, stream>>>((const uint4*)x1, offs, csr, eps3,
                                              (uint4*)hbuf, N, N);
  k_mlp<128,64,64,true><<<Npad/64, 256, 0, stream>>>(hbuf, wperm+57344, b3a, wperm+65536, b3b,
                                                     nullptr, emb, wperm+69632, bfc, outp, N);
}

// Round 4
// 358.816 us; speedup vs baseline: 1.1102x; 1.1102x over previous
//
#include <hip/hip_runtime.h>
#include <hip/hip_bf16.h>
#include <stdint.h>

typedef unsigned short ushort_t;
typedef __attribute__((ext_vector_type(8))) short short8;
typedef __attribute__((ext_vector_type(4))) float floatx4;
typedef __attribute__((ext_vector_type(2))) float floatx2;

__device__ __forceinline__ float bf2f(unsigned short u){
  union { unsigned int i; float f; } v; v.i = ((unsigned int)u) << 16; return v.f;
}
__device__ __forceinline__ unsigned short f2bf(float f){
  union { float f; unsigned int i; } v; v.f = f;
  unsigned int r = v.i + 0x7FFFu + ((v.i >> 16) & 1u);
  return (unsigned short)(r >> 16);
}
__device__ __forceinline__ unsigned int pack2(unsigned short lo, unsigned short hi){
  return ((unsigned int)hi << 16) | (unsigned int)lo;
}
// 2-op bf16-pair unpack: lo half = v<<16, hi half = v & 0xffff0000
__device__ __forceinline__ float bflo(unsigned int v){
  union { unsigned int u; float f; } c; c.u = v << 16; return c.f;
}
__device__ __forceinline__ float bfhi(unsigned int v){
  union { unsigned int u; float f; } c; c.u = v & 0xffff0000u; return c.f;
}
// packed bf16-pair -> float2; accumulate via packed f32 add
__device__ __forceinline__ floatx2 bfpair(unsigned int v){
  union { unsigned int u; float f; } lo, hi;
  lo.u = v << 16; hi.u = v & 0xffff0000u;
  floatx2 r; r.x = lo.f; r.y = hi.f; return r;
}

// ---------------- prep kernel: [bucket histogram | x->bf16 | weight perm] by block range ----------------
// Per-block int64/int32 storage detect: OR 4096 odd words of this block's span
// (int64 storage => all-zero high halves; P(false positive | int32) ~ (1e-5)^2560 ~ 0).
// Weight-perm region includes a 64x64 identity (for mlp3's GEMM1 = bias+relu passthrough).

__global__ __launch_bounds__(256)
void k_prep(const unsigned int* __restrict__ w, int* __restrict__ ghist, int E, int N, int nbB,
            const float2* __restrict__ xin, unsigned int* __restrict__ xb, int total2, int tobfB,
            const float* __restrict__ W1a, const float* __restrict__ W1b, const float* __restrict__ W2a,
            const float* __restrict__ W2b, const float* __restrict__ W3a, const float* __restrict__ W3b,
            const float* __restrict__ Wfc, ushort_t* __restrict__ wout)
{
  int b = blockIdx.x, t = threadIdx.x;
  if (b < nbB){
    __shared__ int h[256];
    __shared__ unsigned int dred[4];
    h[t] = 0;
    int base = b*4096 + t;
    unsigned int acc = 0;
    #pragma unroll
    for (int i=0;i<16;++i){
      int e = base + i*256;
      if (e < E) acc |= w[2*e+1];
    }
    #pragma unroll
    for (int o=32;o>=1;o>>=1) acc |= __shfl_xor(acc, o);
    if ((t&63)==0) dred[t>>6] = acc;
    __syncthreads();
    int m = (dred[0]|dred[1]|dred[2]|dred[3]) != 0;   // 1 => int32 words
    #pragma unroll
    for (int i=0;i<16;++i){
      int e = base + i*256;
      if (e < E){
        int d = m ? (int)w[(size_t)E + e] : (int)w[2*((size_t)E + e)];
        if ((unsigned)d < (unsigned)N) atomicAdd(&h[d>>9], 1);
      }
    }
    __syncthreads();
    if (h[t]) atomicAdd(&ghist[t], h[t]);
  } else if (b < nbB + tobfB){
    int i = (b - nbB)*256 + t;
    if (i < total2){
      float2 v = xin[i];
      xb[i] = pack2(f2bf(v.x), f2bf(v.y));
    }
  } else {
    int id = (b - nbB - tobfB)*256 + t;
    const float* src; int K, M, base2, local;
    if      (id <  8192){ src=W1a; K=64;  M=128; base2=0;     local=id; }
    else if (id < 24576){ src=W1b; K=128; M=128; base2=8192;  local=id-8192; }
    else if (id < 40960){ src=W2a; K=128; M=128; base2=24576; local=id-24576; }
    else if (id < 57344){ src=W2b; K=128; M=128; base2=40960; local=id-40960; }
    else if (id < 65536){ src=W3a; K=128; M=64;  base2=57344; local=id-57344; }
    else if (id < 69632){ src=W3b; K=64;  M=64;  base2=65536; local=id-65536; }
    else if (id < 70656){ src=Wfc; K=64;  M=16;  base2=69632; local=id-69632; }
    else if (id < 74752){ src=nullptr; K=64; M=64; base2=70656; local=id-70656; } // identity
    else return;
    int k = local / M, nn = local - k*M;
    float val;
    if (src == nullptr) val = (k == nn) ? 1.0f : 0.0f;
    else if (src == Wfc) val = (nn<8) ? Wfc[k*8+nn] : 0.0f;
    else                 val = src[k*M+nn];
    int idx = (((nn>>4)*(K/32) + (k>>5))*4 + ((k>>3)&3))*128 + (nn&15)*8 + (k&7);
    wout[base2+idx] = f2bf(val);
  }
}

// ---------------- CSR build via 512-node bucket counting sort ----------------

__global__ __launch_bounds__(256) void k_bscan(const int* __restrict__ ghist, int* __restrict__ bbase,
                                               int* __restrict__ gcur, int NB){
  __shared__ int sv[256];
  int t = threadIdx.x;
  int v = (t < NB) ? ghist[t] : 0;
  sv[t] = v; __syncthreads();
  for (int o=1;o<256;o<<=1){
    int xv = (t>=o)? sv[t-o] : 0;
    __syncthreads();
    sv[t] += xv;
    __syncthreads();
  }
  int excl = sv[t] - v;
  if (t < NB){ bbase[t] = excl; gcur[t] = excl; }
  if (t == NB-1) bbase[NB] = excl + v;
}

__global__ __launch_bounds__(256) void k_bin(const unsigned int* __restrict__ w,
                                             int* __restrict__ gcur, int2* __restrict__ pairs,
                                             int E, int N, int NB){
  __shared__ int h[256];
  __shared__ int cur[256];
  __shared__ unsigned int dred[4];
  int t = threadIdx.x;
  h[t] = 0;
  int base = blockIdx.x*4096 + t;
  unsigned int acc = 0;
  #pragma unroll
  for (int i=0;i<16;++i){
    int e = base + i*256;
    if (e < E) acc |= w[2*e+1];
  }
  #pragma unroll
  for (int o=32;o>=1;o>>=1) acc |= __shfl_xor(acc, o);
  if ((t&63)==0) dred[t>>6] = acc;
  __syncthreads();
  int m = (dred[0]|dred[1]|dred[2]|dred[3]) != 0;
  int d[16], s[16];
  #pragma unroll
  for (int i=0;i<16;++i){
    int e = base + i*256;
    d[i] = -1; s[i] = 0;
    if (e < E){
      if (m){ s[i] = (int)w[e];           d[i] = (int)w[(size_t)E + e]; }
      else  { s[i] = (int)w[2*(size_t)e]; d[i] = (int)w[2*((size_t)E + e)]; }
      if ((unsigned)d[i] >= (unsigned)N || (unsigned)s[i] >= (unsigned)N) d[i] = -1;
    }
  }
  #pragma unroll
  for (int i=0;i<16;++i)
    if (d[i] >= 0) atomicAdd(&h[d[i]>>9], 1);
  __syncthreads();
  if (t < NB && h[t]) cur[t] = atomicAdd(&gcur[t], h[t]);
  __syncthreads();
  #pragma unroll
  for (int i=0;i<16;++i){
    if (d[i] >= 0){
      int p = atomicAdd(&cur[d[i]>>9], 1);
      pairs[p] = make_int2(d[i], s[i]);
    }
  }
}

__global__ __launch_bounds__(256) void k_bcsr(const int2* __restrict__ pairs, const int* __restrict__ bbase,
                                              int* __restrict__ offs, int* __restrict__ csr, int N, int NB){
  __shared__ int cnt[512];
  __shared__ int wsum[4];
  int b = blockIdx.x, t = threadIdx.x, lane = t&63, wv = t>>6;
  int lo = bbase[b], hi = bbase[b+1];
  int node0 = b << 9;
  cnt[t] = 0; cnt[t+256] = 0;
  __syncthreads();
  for (int i = lo+t; i < hi; i += 256){
    int2 p = pairs[i];
    atomicAdd(&cnt[p.x - node0], 1);
  }
  __syncthreads();
  int v0 = cnt[2*t], v1 = cnt[2*t+1], tot = v0+v1;
  int s = tot;
  #pragma unroll
  for (int o=1;o<64;o<<=1){ int xv = __shfl_up(s,o); if (lane>=o) s += xv; }
  if (lane==63) wsum[wv] = s;
  __syncthreads();
  int basev = 0;
  for (int j=0;j<wv;++j) basev += wsum[j];
  int excl = basev + s - tot;
  int e0 = lo + excl, e1 = lo + excl + v0;
  cnt[2*t] = e0; cnt[2*t+1] = e1;
  int n0 = node0 + 2*t, n1 = node0 + 2*t + 1;
  if (n0 < N) offs[n0] = e0;
  if (n1 < N) offs[n1] = e1;
  if (b == NB-1 && t == 255) offs[N] = hi;
  __syncthreads();
  for (int i = lo+t; i < hi; i += 256){
    int2 p = pairs[i];
    int pos = atomicAdd(&cnt[p.x - node0], 1);
    csr[pos] = p.y;
  }
}

// ------------- gather: shfl-distributed csr + uint4 rows + packed-f32 accumulate -------------

template<int F>
__global__ __launch_bounds__(256) void k_gatherx(const uint4* __restrict__ xr, const int* __restrict__ offs,
                                                 const int* __restrict__ csr, const float* __restrict__ epsp,
                                                 uint4* __restrict__ hr, int n, int nzrow){
  constexpr int RS  = F/8;           // uint4 per row: 16 (F=128), 8 (F=64)
  constexpr int LPN = 4*RS;          // lanes per node: 64 (F=128), 32 (F=64)
  constexpr int NPW = 64/LPN;        // nodes per wave: 1 or 2
  constexpr int CH  = LPN;           // csr entries per chunk
  constexpr int MAXG = CH/16;        // groups per chunk: 4 (F=128), 2 (F=64)
  int gt = blockIdx.x*256 + threadIdx.x;
  int wv = gt >> 6, lane = gt & 63;
  int grp = lane / LPN;              // node within wave
  int lin = lane % LPN;              // lane within node
  int q   = lin / RS;                // quarter 0..3
  int f   = lin % RS;                // uint4 index within row
  int node = wv*NPW + grp;
  if (node >= n) return;
  const size_t row = (size_t)node*RS;
  float e1s = 1.0f + epsp[0];
  floatx2 a0,a1,a2,a3;
  if (q == 0){
    uint4 sv = xr[row + f];
    floatx2 es; es.x = e1s; es.y = e1s;
    a0 = es*bfpair(sv.x); a1 = es*bfpair(sv.y);
    a2 = es*bfpair(sv.z); a3 = es*bfpair(sv.w);
  } else {
    floatx2 z; z.x = 0.f; z.y = 0.f;
    a0 = z; a1 = z; a2 = z; a3 = z;
  }
  int u0 = offs[node], u1 = offs[node+1];
  int deg = u1 - u0;

#define ISSUE(g, V0,V1,V2,V3) { int bb = grp*LPN + (g)*16 + q; \
    int s0=__shfl(cv,bb), s1=__shfl(cv,bb+4), s2=__shfl(cv,bb+8), s3=__shfl(cv,bb+12); \
    V0 = xr[(size_t)s0*RS + f]; V1 = xr[(size_t)s1*RS + f]; \
    V2 = xr[(size_t)s2*RS + f]; V3 = xr[(size_t)s3*RS + f]; }
#define ACCV(V)  { a0 += bfpair((V).x); a1 += bfpair((V).y); a2 += bfpair((V).z); a3 += bfpair((V).w); }
#define ACC4(V0,V1,V2,V3) { ACCV(V0) ACCV(V1) ACCV(V2) ACCV(V3) }

  for (int c0 = 0; c0 < deg; c0 += CH){
    int rem = deg - c0;
    int cv = nzrow;                          // padded entries gather the zeroed row
    if (lin < rem) cv = csr[u0 + c0 + lin];  // one coalesced load covers the chunk
    int nk = rem < CH ? rem : CH;
    int ng = (nk + 15) >> 4;                 // uniform within a node
    uint4 A0,A1,A2,A3, B0,B1,B2,B3;
    ISSUE(0, A0,A1,A2,A3)
    if (ng > 1) { ISSUE(1, B0,B1,B2,B3) }
    ACC4(A0,A1,A2,A3)
    if (ng > 1){
      if constexpr (MAXG >= 3) { if (ng > 2) ISSUE(2, A0,A1,A2,A3) }
      ACC4(B0,B1,B2,B3)
      if constexpr (MAXG >= 3){
        if (ng > 2){
          if (ng > 3) { ISSUE(3, B0,B1,B2,B3) }
          ACC4(A0,A1,A2,A3)
          if (ng > 3) { ACC4(B0,B1,B2,B3) }
        }
      }
    }
  }
#undef ISSUE
#undef ACCV
#undef ACC4
  // reduce partial sums across the 4 quarter-groups
#define RED(av) { av.x += __shfl_xor(av.x, RS);   av.y += __shfl_xor(av.y, RS); \
                  av.x += __shfl_xor(av.x, 2*RS); av.y += __shfl_xor(av.y, 2*RS); }
  RED(a0) RED(a1) RED(a2) RED(a3)
#undef RED
  if (q == 0){
    uint4 o;
    o.x = pack2(f2bf(a0.x), f2bf(a0.y));
    o.y = pack2(f2bf(a1.x), f2bf(a1.y));
    o.z = pack2(f2bf(a2.x), f2bf(a2.y));
    o.w = pack2(f2bf(a3.x), f2bf(a3.y));
    hr[row + f] = o;
  }
}

// ---------------- fused MFMA MLP ----------------
// x_next = relu(relu(h@Wa+ba)@Wb+bb)
// Y3:   additionally y3 = x_next @ W3a (wpfc carries W3a-perm, 128->64, linear only) and
//       ONLY y3 is written (64-wide) -- layer-3 gather then runs on y3 (halved traffic).
// LAST: emb(f32) + FC GEMM -> out(f32).

template<int F, int M1, int M2, bool LAST, bool Y3>
__global__ __launch_bounds__(256)
void k_mlp(const ushort_t* __restrict__ h,
           const ushort_t* __restrict__ wp1, const float* __restrict__ b1,
           const ushort_t* __restrict__ wp2, const float* __restrict__ b2,
           ushort_t* __restrict__ xout,      // !LAST: bf16 next-layer x (Y3: y3, 64-wide)
           float* __restrict__ embp,         // LAST: f32 emb
           const ushort_t* __restrict__ wpfc, const float* __restrict__ bfc,
           float* __restrict__ outp, int n)
{
  constexpr int NT1 = M1/16, NT2 = M2/16, KC1 = F/32, KC2 = M1/32;
  __shared__ short sC1[4*(M1/8)*136];
  __shared__ short sX3[LAST ? (4*8*136) : 1];
  int tid = threadIdx.x, lane = tid&63, w = tid>>6;
  int m16 = lane&15, quad = lane>>4;
  int row0 = blockIdx.x*64 + w*16;
  size_t arow = (size_t)(row0 + m16);

  floatx4 acc[NT1];
  #pragma unroll
  for (int i=0;i<NT1;++i) acc[i] = (floatx4){0.f,0.f,0.f,0.f};
  #pragma unroll
  for (int kc=0; kc<KC1; ++kc){
    short8 a = *(const short8*)(h + arow*F + kc*32 + quad*8);
    #pragma unroll
    for (int nt=0; nt<NT1; ++nt){
      short8 b = *(const short8*)(wp1 + (size_t)((nt*KC1+kc)*64 + lane)*8);
      acc[nt] = __builtin_amdgcn_mfma_f32_16x16x32_bf16(a, b, acc[nt], 0, 0, 0);
    }
  }
  #pragma unroll
  for (int nt=0; nt<NT1; ++nt){
    int c = nt*16 + m16;
    float bias = b1[c];
    #pragma unroll
    for (int r=0;r<4;++r){
      float v = fmaxf(acc[nt][r] + bias, 0.f);
      int mm = quad*4 + r;
      sC1[(w*(M1/8) + (c>>3))*136 + mm*8 + (c&7)] = (short)f2bf(v);
    }
  }
  __syncthreads();

  floatx4 acc2[NT2];
  #pragma unroll
  for (int i=0;i<NT2;++i) acc2[i] = (floatx4){0.f,0.f,0.f,0.f};
  #pragma unroll
  for (int kc=0; kc<KC2; ++kc){
    short8 a = *(const short8*)&sC1[(w*(M1/8) + kc*4 + quad)*136 + m16*8];
    #pragma unroll
    for (int nt=0; nt<NT2; ++nt){
      short8 b = *(const short8*)(wp2 + (size_t)((nt*KC2+kc)*64 + lane)*8);
      acc2[nt] = __builtin_amdgcn_mfma_f32_16x16x32_bf16(a, b, acc2[nt], 0, 0, 0);
    }
  }
  #pragma unroll
  for (int nt=0; nt<NT2; ++nt){
    int c = nt*16 + m16;
    float bias = b2[c];
    #pragma unroll
    for (int r=0;r<4;++r){
      float v = fmaxf(acc2[nt][r] + bias, 0.f);
      int mm = quad*4 + r;
      int row = row0 + mm;
      if constexpr (Y3){
        // stage x2 into sC1 (per-warp section; in-order DS pipe makes the overwrite safe)
        sC1[(w*(M2/8) + (c>>3))*136 + mm*8 + (c&7)] = (short)f2bf(v);
      } else if constexpr (!LAST){
        if (row < n) xout[(size_t)row*M2 + c] = f2bf(v);
      } else {
        if (row < n) embp[(size_t)row*64 + c] = v;                // f32 emb
        sX3[(w*8 + (c>>3))*136 + mm*8 + (c&7)] = (short)f2bf(v);
      }
    }
  }

  if constexpr (Y3){
    // y3 = x2 @ W3a (M2=128 -> 64), linear only (bias+relu applied later via identity GEMM)
    constexpr int KC3 = M2/32;
    floatx4 acc3[4];
    #pragma unroll
    for (int i=0;i<4;++i) acc3[i] = (floatx4){0.f,0.f,0.f,0.f};
    #pragma unroll
    for (int kc=0; kc<KC3; ++kc){
      short8 a = *(const short8*)&sC1[(w*(M2/8) + kc*4 + quad)*136 + m16*8];
      #pragma unroll
      for (int nt=0; nt<4; ++nt){
        short8 b = *(const short8*)(wpfc + (size_t)((nt*KC3+kc)*64 + lane)*8);
        acc3[nt] = __builtin_amdgcn_mfma_f32_16x16x32_bf16(a, b, acc3[nt], 0, 0, 0);
      }
    }
    #pragma unroll
    for (int nt=0; nt<4; ++nt){
      int c = nt*16 + m16;
      #pragma unroll
      for (int r=0;r<4;++r){
        int row = row0 + quad*4 + r;
        if (row < n) xout[(size_t)row*64 + c] = f2bf(acc3[nt][r]);
      }
    }
  }

  if constexpr (LAST){
    __syncthreads();
    floatx4 accf = (floatx4){0.f,0.f,0.f,0.f};
    #pragma unroll
    for (int kc=0; kc<2; ++kc){
      short8 a = *(const short8*)&sX3[(w*8 + kc*4 + quad)*136 + m16*8];
      short8 b = *(const short8*)(wpfc + (size_t)(kc*64 + lane)*8);
      accf = __builtin_amdgcn_mfma_f32_16x16x32_bf16(a, b, accf, 0, 0, 0);
    }
    if (m16 < 8){
      float bias = bfc[m16];
      #pragma unroll
      for (int r=0;r<4;++r){
        int row = row0 + quad*4 + r;
        if (row < n) outp[(size_t)row*8 + m16] = accf[r] + bias;  // f32 out
      }
    }
  }
}

// ---------------- launcher ----------------

extern "C" void kernel_launch(void* const* d_in, const int* in_sizes, int n_in,
                              void* d_out, int out_size, void* d_ws, size_t ws_size,
                              hipStream_t stream)
{
  const int N = in_sizes[0] / 64;
  const int E = in_sizes[1] / 2;
  const int NB = (N + 511) / 512;
  const float*        x    = (const float*)d_in[0];
  const unsigned int* ew   = (const unsigned int*)d_in[1];
  const float* eps1 = (const float*)d_in[2];
  const float* eps2 = (const float*)d_in[3];
  const float* eps3 = (const float*)d_in[4];
  const float* W1a  = (const float*)d_in[5];
  const float* b1a  = (const float*)d_in[6];
  const float* W1b  = (const float*)d_in[7];
  const float* b1b  = (const float*)d_in[8];
  const float* W2a  = (const float*)d_in[9];
  const float* b2a  = (const float*)d_in[10];
  const float* W2b  = (const float*)d_in[11];
  const float* b2b  = (const float*)d_in[12];
  const float* W3a  = (const float*)d_in[13];
  const float* b3a  = (const float*)d_in[14];
  const float* W3b  = (const float*)d_in[15];
  const float* b3b  = (const float*)d_in[16];
  const float* Wfc  = (const float*)d_in[17];
  const float* bfc  = (const float*)d_in[18];

  float* outp = (float*)d_out;                 // f32 output (verified round 6)
  float* emb  = outp + (size_t)N*8;

  const int Npad = ((N + 63)/64)*64;

  char* ws = (char*)d_ws;
  size_t o = 0;
  auto alloc = [&](size_t bytes)->char* {
    char* p = ws + o;
    o = (o + bytes + 255) & ~(size_t)255;
    return p;
  };
  int*      ghist = (int*)alloc(256*4);
  int*      bbase = (int*)alloc(257*4);
  int*      gcur  = (int*)alloc(256*4);
  int*      offs  = (int*)alloc((size_t)(N+1)*4);
  int2*     pairs = (int2*)alloc((size_t)E*8);
  int*      csr   = (int*)alloc((size_t)E*4);
  ushort_t* wperm = (ushort_t*)alloc(74752ull*2);
  ushort_t* xb    = (ushort_t*)alloc(((size_t)Npad + 64)*64*2);    // bf16 copy of x (+zero row)
  ushort_t* hbuf  = (ushort_t*)alloc((size_t)Npad*128*2);          // gather output (bf16)
  ushort_t* x1    = (ushort_t*)alloc(((size_t)Npad + 64)*128*2);   // layer-1 output (bf16, +zero row)
  ushort_t* ybuf  = (ushort_t*)alloc(((size_t)Npad + 64)*64*2);    // y3 = x2@W3a (bf16, +zero row)

  hipMemsetAsync(ghist, 0, 256*4, stream);
  // zero dummy rows (index N) used by the gather for padded edge slots
  hipMemsetAsync(xb + (size_t)N*64, 0, 64*2, stream);
  hipMemsetAsync(x1 + (size_t)N*128, 0, 128*2, stream);
  hipMemsetAsync(ybuf + (size_t)N*64, 0, 64*2, stream);
  const int nbB   = (E + 4095)/4096;
  const int tobfB = (N*32 + 255)/256;
  const int permB = 74752/256;
  k_prep<<<nbB + tobfB + permB, 256, 0, stream>>>(ew, ghist, E, N, nbB,
                                                  (const float2*)x, (unsigned int*)xb, N*32, tobfB,
                                                  W1a, W1b, W2a, W2b, W3a, W3b, Wfc, wperm);
  k_bscan<<<1, 256, 0, stream>>>(ghist, bbase, gcur, NB);
  k_bin<<<nbB, 256, 0, stream>>>(ew, gcur, pairs, E, N, NB);
  k_bcsr<<<NB, 256, 0, stream>>>(pairs, bbase, offs, csr, N, NB);

  // layer 1 (64 -> 128): gather F=64 (2 nodes/wave)
  k_gatherx<64><<<(N+7)/8, 256, 0, stream>>>((const uint4*)xb, offs, csr, eps1,
                                             (uint4*)hbuf, N, N);
  k_mlp<64,128,128,false,false><<<Npad/64, 256, 0, stream>>>(hbuf, wperm+0, b1a, wperm+8192, b1b,
                                                             x1, nullptr, nullptr, nullptr, nullptr, N);
  // layer 2 (128 -> 128) + y3 = x2@W3a pre-transform (128 -> 64)
  k_gatherx<128><<<(N+3)/4, 256, 0, stream>>>((const uint4*)x1, offs, csr, eps2,
                                              (uint4*)hbuf, N, N);
  k_mlp<128,128,128,false,true><<<Npad/64, 256, 0, stream>>>(hbuf, wperm+24576, b2a, wperm+40960, b2b,
                                                             ybuf, nullptr, wperm+57344, nullptr, nullptr, N);
  // layer 3: gather on y3 (F=64, halved traffic), then identity-GEMM1 (bias+relu) + W3b + FC
  k_gatherx<64><<<(N+7)/8, 256, 0, stream>>>((const uint4*)ybuf, offs, csr, eps3,
                                             (uint4*)hbuf, N, N);
  k_mlp<64,64,64,true,false><<<Npad/64, 256, 0, stream>>>(hbuf, wperm+70656, b3a, wperm+65536, b3b,
                                                          nullptr, emb, wperm+69632, bfc, outp, N);
}